// Round 6
// baseline (687.805 us; speedup 1.0000x reference)
//
#include <hip/hip_runtime.h>
#include <math.h>

// GCN 2-layer forward, bucketed CSR build + pull-mode aggregation.
// Round 6: round-5 pull structure, with col[] read via scalar (wave-uniform)
// int loads to avoid misaligned int2 loads (start has arbitrary parity).
//
// ws layout (byte offsets, MiB = 1<<20):
//   0        : bcnt[B]       (i32)
//   16KB     : boff[B+1]     (i32)
//   64KB     : dinv[N]       (f32)
//   512KB    : rowptr[N+1]   (i32)
//   1MiB     : col[E]        (i32)             ~12.2 MiB
//   14MiB    : h[N*128]      (f32)             ~48.9 MiB
//   63MiB    : agg[N*128]    (f32)             ~48.9 MiB  (written after build)
//   63MiB    : staging[B*5120] (i32, ~15.3MiB) OVERLAPS agg: dead before agg written

#define MB (1u << 20)
#define BCAP 5120

__global__ __launch_bounds__(256) void k_append(const int* __restrict__ src,
                                                const int* __restrict__ dst,
                                                int* __restrict__ bcnt,
                                                int* __restrict__ staging,
                                                int E, int N, int B) {
  __shared__ int lh[1024];
  __shared__ int lb[1024];
  const int t = threadIdx.x;
  const int per = (E + gridDim.x - 1) / gridDim.x;
  const int e0 = blockIdx.x * per;
  const int e1 = min(e0 + per, E);

  for (int i = t; i < B; i += 256) lh[i] = 0;
  __syncthreads();
  for (int e = e0 + t; e < e1; e += 256) {
    int d = dst[e], s = src[e];
    if ((unsigned)d < (unsigned)N && (unsigned)s < (unsigned)N)
      atomicAdd(&lh[d >> 7], 1);
  }
  __syncthreads();
  for (int i = t; i < B; i += 256) {
    int c = lh[i];
    lb[i] = c ? atomicAdd(&bcnt[i], c) : 0;
  }
  __syncthreads();
  for (int i = t; i < B; i += 256) lh[i] = 0;
  __syncthreads();
  for (int e = e0 + t; e < e1; e += 256) {
    int d = dst[e], s = src[e];
    if ((unsigned)d < (unsigned)N && (unsigned)s < (unsigned)N) {
      int b = d >> 7;
      int lp = atomicAdd(&lh[b], 1);
      int pos = lb[b] + lp;
      if (pos < BCAP)
        staging[(size_t)b * BCAP + pos] = ((d & 127) << 25) | s;
    }
  }
}

__global__ __launch_bounds__(256) void k_bscan(const int* __restrict__ bcnt,
                                               int* __restrict__ boff,
                                               int* __restrict__ rowptr,
                                               int B, int N) {
  __shared__ int sh[256];
  const int t = threadIdx.x;
  const int per = (B + 255) / 256;
  const int base = t * per;
  int s = 0;
  for (int j = 0; j < per; j++) {
    int i = base + j;
    if (i < B) s += min(bcnt[i], BCAP);
  }
  sh[t] = s;
  __syncthreads();
  for (int d = 1; d < 256; d <<= 1) {
    int v = (t >= d) ? sh[t - d] : 0;
    __syncthreads();
    sh[t] += v;
    __syncthreads();
  }
  int excl = (t == 0) ? 0 : sh[t - 1];
  for (int j = 0; j < per; j++) {
    int i = base + j;
    if (i < B) {
      boff[i] = excl;
      excl += min(bcnt[i], BCAP);
    }
  }
  if (t == 255) {
    boff[B] = sh[255];
    rowptr[N] = sh[255];
  }
}

__global__ __launch_bounds__(256) void k_build(const int* __restrict__ staging,
                                               const int* __restrict__ bcnt,
                                               const int* __restrict__ boff,
                                               int* __restrict__ rowptr,
                                               float* __restrict__ dinv,
                                               int* __restrict__ col, int N) {
  __shared__ int cnts[128];
  __shared__ int off[128];
  __shared__ int cur[128];
  const int b = blockIdx.x;
  const int t = threadIdx.x;
  int cnt = min(bcnt[b], BCAP);
  const int* stg = staging + (size_t)b * BCAP;

  if (t < 128) cnts[t] = 0;
  __syncthreads();
  for (int i = t; i < cnt; i += 256)
    atomicAdd(&cnts[((unsigned)stg[i]) >> 25], 1);
  __syncthreads();
  if (t < 128) off[t] = cnts[t];
  __syncthreads();
  for (int d = 1; d < 128; d <<= 1) {
    int v = 0;
    if (t < 128 && t >= d) v = off[t - d];
    __syncthreads();
    if (t < 128) off[t] += v;
    __syncthreads();
  }
  const int ebase = boff[b];
  if (t < 128) {
    int node = b * 128 + t;
    if (node < N) {
      int ex = off[t] - cnts[t];
      rowptr[node] = ebase + ex;
      cur[t] = ex;
      dinv[node] = rsqrtf((float)(cnts[t] + 1));
    }
  }
  __syncthreads();
  for (int i = t; i < cnt; i += 256) {
    int p = stg[i];
    int dl = ((unsigned)p) >> 25;
    int s = p & 0x1FFFFFF;
    int lp = atomicAdd(&cur[dl], 1);
    col[ebase + lp] = s;
  }
}

// H[M x 128] = act(X)[M x 128] @ W[128 x 128], scaled by dinv[row].
template <bool RELU_IN>
__global__ __launch_bounds__(256) void k_gemm(const float* __restrict__ X,
                                              const float* __restrict__ W,
                                              const float* __restrict__ dinv,
                                              float* __restrict__ H, int M) {
  __shared__ float Xs[64 * 128];
  __shared__ float Ws[128 * 64];
  const int rb = blockIdx.x * 64;
  const int cb = blockIdx.y * 64;
  const int t = threadIdx.x;

  for (int id = t; id < 64 * 32; id += 256) {
    int r = id >> 5, g = id & 31;
    int row = rb + r;
    float4 v = make_float4(0.f, 0.f, 0.f, 0.f);
    if (row < M) {
      v = *reinterpret_cast<const float4*>(X + (size_t)row * 128 + g * 4);
      if (RELU_IN) {
        v.x = fmaxf(v.x, 0.f); v.y = fmaxf(v.y, 0.f);
        v.z = fmaxf(v.z, 0.f); v.w = fmaxf(v.w, 0.f);
      }
    }
    *reinterpret_cast<float4*>(&Xs[r * 128 + ((g ^ (r & 7)) << 2)]) = v;
  }
  for (int id = t; id < 128 * 16; id += 256) {
    int k = id >> 4, g = id & 15;
    *reinterpret_cast<float4*>(&Ws[k * 64 + g * 4]) =
        *reinterpret_cast<const float4*>(W + k * 128 + cb + g * 4);
  }
  __syncthreads();

  const int tc = t & 15;
  const int tr = t >> 4;
  float acc[4][4] = {};

  for (int k0 = 0; k0 < 128; k0 += 4) {
    float xr[4][4];
    #pragma unroll
    for (int i = 0; i < 4; i++) {
      int r = tr * 4 + i;
      *reinterpret_cast<float4*>(xr[i]) = *reinterpret_cast<const float4*>(
          &Xs[r * 128 + ((((k0 >> 2) ^ (r & 7))) << 2)]);
    }
    #pragma unroll
    for (int kk = 0; kk < 4; kk++) {
      float wv[4];
      #pragma unroll
      for (int j = 0; j < 4; j++) wv[j] = Ws[(k0 + kk) * 64 + tc + 16 * j];
      #pragma unroll
      for (int i = 0; i < 4; i++) {
        #pragma unroll
        for (int j = 0; j < 4; j++) acc[i][j] += xr[i][kk] * wv[j];
      }
    }
  }

  #pragma unroll
  for (int i = 0; i < 4; i++) {
    int row = rb + tr * 4 + i;
    if (row < M) {
      float dv = dinv[row];
      #pragma unroll
      for (int j = 0; j < 4; j++)
        H[(size_t)row * 128 + cb + tc + 16 * j] = acc[i][j] * dv;
    }
  }
}

// out[i] = dinv[i]*(hs[i] + sum_j hs[col_j]) + b ; optional ReLU.
// One wave per node; float4/lane, 32 lanes per row -> 2 edges per instruction.
template <bool RELU_OUT>
__global__ __launch_bounds__(256) void k_pull(const float* __restrict__ hs,
                                              const int* __restrict__ rowptr,
                                              const int* __restrict__ col,
                                              const float* __restrict__ dinv,
                                              const float* __restrict__ bias,
                                              float* __restrict__ out, int N) {
  int node = blockIdx.x * 4 + (threadIdx.x >> 6);
  if (node >= N) return;
  node = __builtin_amdgcn_readfirstlane(node);
  const int lane = threadIdx.x & 63;
  const int half = lane >> 5;
  const int fo = (lane & 31) << 2;  // feature offset (float4 granule)
  const int start = __builtin_amdgcn_readfirstlane(rowptr[node]);
  const int cnt = __builtin_amdgcn_readfirstlane(rowptr[node + 1]) - start;

  float4 a0 = make_float4(0.f, 0.f, 0.f, 0.f);
  float4 a1 = a0, a2 = a0, a3 = a0;

  int k = 0;
  for (; k + 8 <= cnt; k += 8) {
    // col reads are wave-uniform scalar loads (SMEM path), 4B-aligned.
    int s0 = col[start + k + 0 + half];
    int s1 = col[start + k + 2 + half];
    int s2 = col[start + k + 4 + half];
    int s3 = col[start + k + 6 + half];
    float4 v0 = *reinterpret_cast<const float4*>(hs + (size_t)s0 * 128 + fo);
    float4 v1 = *reinterpret_cast<const float4*>(hs + (size_t)s1 * 128 + fo);
    float4 v2 = *reinterpret_cast<const float4*>(hs + (size_t)s2 * 128 + fo);
    float4 v3 = *reinterpret_cast<const float4*>(hs + (size_t)s3 * 128 + fo);
    a0.x += v0.x; a0.y += v0.y; a0.z += v0.z; a0.w += v0.w;
    a1.x += v1.x; a1.y += v1.y; a1.z += v1.z; a1.w += v1.w;
    a2.x += v2.x; a2.y += v2.y; a2.z += v2.z; a2.w += v2.w;
    a3.x += v3.x; a3.y += v3.y; a3.z += v3.z; a3.w += v3.w;
  }
  for (; k + 2 <= cnt; k += 2) {
    int s = col[start + k + half];
    float4 v = *reinterpret_cast<const float4*>(hs + (size_t)s * 128 + fo);
    a0.x += v.x; a0.y += v.y; a0.z += v.z; a0.w += v.w;
  }
  if (k < cnt) {  // odd tail: both halves load same row; count it in half 0 only
    int s = col[start + k];
    float4 v = *reinterpret_cast<const float4*>(hs + (size_t)s * 128 + fo);
    if (!half) {
      a1.x += v.x; a1.y += v.y; a1.z += v.z; a1.w += v.w;
    }
  }
  float4 acc;
  acc.x = (a0.x + a1.x) + (a2.x + a3.x);
  acc.y = (a0.y + a1.y) + (a2.y + a3.y);
  acc.z = (a0.z + a1.z) + (a2.z + a3.z);
  acc.w = (a0.w + a1.w) + (a2.w + a3.w);
  // cross-half combine: lanes l and l^32 hold same features, disjoint edges
  acc.x += __shfl_xor(acc.x, 32, 64);
  acc.y += __shfl_xor(acc.y, 32, 64);
  acc.z += __shfl_xor(acc.z, 32, 64);
  acc.w += __shfl_xor(acc.w, 32, 64);

  if (!half) {
    float4 self = *reinterpret_cast<const float4*>(hs + (size_t)node * 128 + fo);
    float di = dinv[node];
    float4 bv = *reinterpret_cast<const float4*>(bias + fo);
    float4 o;
    o.x = fmaf(di, acc.x + self.x, bv.x);
    o.y = fmaf(di, acc.y + self.y, bv.y);
    o.z = fmaf(di, acc.z + self.z, bv.z);
    o.w = fmaf(di, acc.w + self.w, bv.w);
    if (RELU_OUT) {
      o.x = fmaxf(o.x, 0.f); o.y = fmaxf(o.y, 0.f);
      o.z = fmaxf(o.z, 0.f); o.w = fmaxf(o.w, 0.f);
    }
    *reinterpret_cast<float4*>(out + (size_t)node * 128 + fo) = o;
  }
}

extern "C" void kernel_launch(void* const* d_in, const int* in_sizes, int n_in,
                              void* d_out, int out_size, void* d_ws, size_t ws_size,
                              hipStream_t stream) {
  const float* x  = (const float*)d_in[0];
  const int*   ei = (const int*)d_in[1];
  const float* W1 = (const float*)d_in[2];
  const float* b1 = (const float*)d_in[3];
  const float* W2 = (const float*)d_in[4];
  const float* b2 = (const float*)d_in[5];
  float* out = (float*)d_out;

  const int N = in_sizes[0] / 128;
  const int E = in_sizes[1] / 2;
  const int B = (N + 127) >> 7;
  const int* src = ei;
  const int* dst = ei + E;

  char* ws = (char*)d_ws;
  int*   bcnt    = (int*)  (ws);
  int*   boff    = (int*)  (ws + 16 * 1024);
  float* dinv    = (float*)(ws + 64 * 1024);
  int*   rowptr  = (int*)  (ws + 512 * 1024);
  int*   col     = (int*)  (ws + 1 * MB);
  float* h       = (float*)(ws + 14 * MB);
  float* agg     = (float*)(ws + 63 * MB);
  int*   staging = (int*)  (ws + 63 * MB);  // overlaps agg; dead before agg written

  dim3 b256(256);

  hipMemsetAsync(bcnt, 0, (size_t)B * 4, stream);
  k_append<<<512, b256, 0, stream>>>(src, dst, bcnt, staging, E, N, B);
  k_bscan<<<1, b256, 0, stream>>>(bcnt, boff, rowptr, B, N);
  k_build<<<B, b256, 0, stream>>>(staging, bcnt, boff, rowptr, dinv, col, N);

  dim3 ggrid((N + 63) / 64, 2);
  dim3 pgrid((N + 3) / 4);

  k_gemm<false><<<ggrid, b256, 0, stream>>>(x, W1, dinv, h, N);
  k_pull<false><<<pgrid, b256, 0, stream>>>(h, rowptr, col, dinv, b1, agg, N);

  k_gemm<true><<<ggrid, b256, 0, stream>>>(agg, W2, dinv, h, N);
  k_pull<true><<<pgrid, b256, 0, stream>>>(h, rowptr, col, dinv, b2, out, N);
}

// Round 7
// 460.991 us; speedup vs baseline: 1.4920x; 1.4920x over previous
//
#include <hip/hip_runtime.h>
#include <hip/hip_fp16.h>
#include <math.h>

// GCN 2-layer forward, bucketed CSR build + pull-mode aggregation.
// Round 7: h stored as fp16 -> halves the L3 gather bytes in k_pull
// (the measured ~7.3 TB/s fabric ceiling is the current wall).
//
// ws layout (byte offsets, MiB = 1<<20):
//   0        : bcnt[B]       (i32)
//   16KB     : boff[B+1]     (i32)
//   64KB     : dinv[N]       (f32)
//   512KB    : rowptr[N+1]   (i32)
//   1MiB     : col[E]        (i32)             ~12.2 MiB
//   14MiB    : h[N*128]      (f16)             ~24.4 MiB
//   63MiB    : agg[N*128]    (f32)             ~48.9 MiB  (written after build)
//   63MiB    : staging[B*5120] (i32, ~15.3MiB) OVERLAPS agg: dead before agg written

#define MB (1u << 20)
#define BCAP 5120

__global__ __launch_bounds__(256) void k_append(const int* __restrict__ src,
                                                const int* __restrict__ dst,
                                                int* __restrict__ bcnt,
                                                int* __restrict__ staging,
                                                int E, int N, int B) {
  __shared__ int lh[1024];
  __shared__ int lb[1024];
  const int t = threadIdx.x;
  const int per = (E + gridDim.x - 1) / gridDim.x;
  const int e0 = blockIdx.x * per;
  const int e1 = min(e0 + per, E);

  for (int i = t; i < B; i += 256) lh[i] = 0;
  __syncthreads();
  for (int e = e0 + t; e < e1; e += 256) {
    int d = dst[e], s = src[e];
    if ((unsigned)d < (unsigned)N && (unsigned)s < (unsigned)N)
      atomicAdd(&lh[d >> 7], 1);
  }
  __syncthreads();
  for (int i = t; i < B; i += 256) {
    int c = lh[i];
    lb[i] = c ? atomicAdd(&bcnt[i], c) : 0;
  }
  __syncthreads();
  for (int i = t; i < B; i += 256) lh[i] = 0;
  __syncthreads();
  for (int e = e0 + t; e < e1; e += 256) {
    int d = dst[e], s = src[e];
    if ((unsigned)d < (unsigned)N && (unsigned)s < (unsigned)N) {
      int b = d >> 7;
      int lp = atomicAdd(&lh[b], 1);
      int pos = lb[b] + lp;
      if (pos < BCAP)
        staging[(size_t)b * BCAP + pos] = ((d & 127) << 25) | s;
    }
  }
}

__global__ __launch_bounds__(256) void k_bscan(const int* __restrict__ bcnt,
                                               int* __restrict__ boff,
                                               int* __restrict__ rowptr,
                                               int B, int N) {
  __shared__ int sh[256];
  const int t = threadIdx.x;
  const int per = (B + 255) / 256;
  const int base = t * per;
  int s = 0;
  for (int j = 0; j < per; j++) {
    int i = base + j;
    if (i < B) s += min(bcnt[i], BCAP);
  }
  sh[t] = s;
  __syncthreads();
  for (int d = 1; d < 256; d <<= 1) {
    int v = (t >= d) ? sh[t - d] : 0;
    __syncthreads();
    sh[t] += v;
    __syncthreads();
  }
  int excl = (t == 0) ? 0 : sh[t - 1];
  for (int j = 0; j < per; j++) {
    int i = base + j;
    if (i < B) {
      boff[i] = excl;
      excl += min(bcnt[i], BCAP);
    }
  }
  if (t == 255) {
    boff[B] = sh[255];
    rowptr[N] = sh[255];
  }
}

__global__ __launch_bounds__(256) void k_build(const int* __restrict__ staging,
                                               const int* __restrict__ bcnt,
                                               const int* __restrict__ boff,
                                               int* __restrict__ rowptr,
                                               float* __restrict__ dinv,
                                               int* __restrict__ col, int N) {
  __shared__ int cnts[128];
  __shared__ int off[128];
  __shared__ int cur[128];
  const int b = blockIdx.x;
  const int t = threadIdx.x;
  int cnt = min(bcnt[b], BCAP);
  const int* stg = staging + (size_t)b * BCAP;

  if (t < 128) cnts[t] = 0;
  __syncthreads();
  for (int i = t; i < cnt; i += 256)
    atomicAdd(&cnts[((unsigned)stg[i]) >> 25], 1);
  __syncthreads();
  if (t < 128) off[t] = cnts[t];
  __syncthreads();
  for (int d = 1; d < 128; d <<= 1) {
    int v = 0;
    if (t < 128 && t >= d) v = off[t - d];
    __syncthreads();
    if (t < 128) off[t] += v;
    __syncthreads();
  }
  const int ebase = boff[b];
  if (t < 128) {
    int node = b * 128 + t;
    if (node < N) {
      int ex = off[t] - cnts[t];
      rowptr[node] = ebase + ex;
      cur[t] = ex;
      dinv[node] = rsqrtf((float)(cnts[t] + 1));
    }
  }
  __syncthreads();
  for (int i = t; i < cnt; i += 256) {
    int p = stg[i];
    int dl = ((unsigned)p) >> 25;
    int s = p & 0x1FFFFFF;
    int lp = atomicAdd(&cur[dl], 1);
    col[ebase + lp] = s;
  }
}

// H[M x 128] = act(X)[M x 128] @ W[128 x 128], scaled by dinv[row], fp16 out.
template <bool RELU_IN>
__global__ __launch_bounds__(256) void k_gemm(const float* __restrict__ X,
                                              const float* __restrict__ W,
                                              const float* __restrict__ dinv,
                                              __half* __restrict__ H, int M) {
  __shared__ float Xs[64 * 128];
  __shared__ float Ws[128 * 64];
  const int rb = blockIdx.x * 64;
  const int cb = blockIdx.y * 64;
  const int t = threadIdx.x;

  for (int id = t; id < 64 * 32; id += 256) {
    int r = id >> 5, g = id & 31;
    int row = rb + r;
    float4 v = make_float4(0.f, 0.f, 0.f, 0.f);
    if (row < M) {
      v = *reinterpret_cast<const float4*>(X + (size_t)row * 128 + g * 4);
      if (RELU_IN) {
        v.x = fmaxf(v.x, 0.f); v.y = fmaxf(v.y, 0.f);
        v.z = fmaxf(v.z, 0.f); v.w = fmaxf(v.w, 0.f);
      }
    }
    *reinterpret_cast<float4*>(&Xs[r * 128 + ((g ^ (r & 7)) << 2)]) = v;
  }
  for (int id = t; id < 128 * 16; id += 256) {
    int k = id >> 4, g = id & 15;
    *reinterpret_cast<float4*>(&Ws[k * 64 + g * 4]) =
        *reinterpret_cast<const float4*>(W + k * 128 + cb + g * 4);
  }
  __syncthreads();

  const int tc = t & 15;
  const int tr = t >> 4;
  float acc[4][4] = {};

  for (int k0 = 0; k0 < 128; k0 += 4) {
    float xr[4][4];
    #pragma unroll
    for (int i = 0; i < 4; i++) {
      int r = tr * 4 + i;
      *reinterpret_cast<float4*>(xr[i]) = *reinterpret_cast<const float4*>(
          &Xs[r * 128 + ((((k0 >> 2) ^ (r & 7))) << 2)]);
    }
    #pragma unroll
    for (int kk = 0; kk < 4; kk++) {
      float wv[4];
      #pragma unroll
      for (int j = 0; j < 4; j++) wv[j] = Ws[(k0 + kk) * 64 + tc + 16 * j];
      #pragma unroll
      for (int i = 0; i < 4; i++) {
        #pragma unroll
        for (int j = 0; j < 4; j++) acc[i][j] += xr[i][kk] * wv[j];
      }
    }
  }

  #pragma unroll
  for (int i = 0; i < 4; i++) {
    int row = rb + tr * 4 + i;
    if (row < M) {
      float dv = dinv[row];
      #pragma unroll
      for (int j = 0; j < 4; j++)
        H[(size_t)row * 128 + cb + tc + 16 * j] = __float2half(acc[i][j] * dv);
    }
  }
}

// out[i] = dinv[i]*(hs[i] + sum_j hs[col_j]) + b ; optional ReLU.
// One wave per node; 32 lanes per row, 4 fp16 (8B) per lane -> 2 edges/instr.
template <bool RELU_OUT>
__global__ __launch_bounds__(256) void k_pull(const __half* __restrict__ hs,
                                              const int* __restrict__ rowptr,
                                              const int* __restrict__ col,
                                              const float* __restrict__ dinv,
                                              const float* __restrict__ bias,
                                              float* __restrict__ out, int N) {
  int node = blockIdx.x * 4 + (threadIdx.x >> 6);
  if (node >= N) return;
  node = __builtin_amdgcn_readfirstlane(node);
  const int lane = threadIdx.x & 63;
  const int half = lane >> 5;
  const int fo = (lane & 31) << 2;  // feature offset (4 halfs / 8B per lane)
  const int start = __builtin_amdgcn_readfirstlane(rowptr[node]);
  const int cnt = __builtin_amdgcn_readfirstlane(rowptr[node + 1]) - start;

  float4 a0 = make_float4(0.f, 0.f, 0.f, 0.f);
  float4 a1 = a0, a2 = a0, a3 = a0;

#define GATHER(sidx, dstacc)                                                   \
  {                                                                            \
    const __half2* p_ =                                                        \
        reinterpret_cast<const __half2*>(hs + (size_t)(sidx) * 128 + fo);      \
    float2 f0_ = __half22float2(p_[0]);                                        \
    float2 f1_ = __half22float2(p_[1]);                                        \
    dstacc.x += f0_.x; dstacc.y += f0_.y;                                      \
    dstacc.z += f1_.x; dstacc.w += f1_.y;                                      \
  }

  int k = 0;
  for (; k + 8 <= cnt; k += 8) {
    int s0 = col[start + k + 0 + half];
    int s1 = col[start + k + 2 + half];
    int s2 = col[start + k + 4 + half];
    int s3 = col[start + k + 6 + half];
    GATHER(s0, a0);
    GATHER(s1, a1);
    GATHER(s2, a2);
    GATHER(s3, a3);
  }
  for (; k + 2 <= cnt; k += 2) {
    int s = col[start + k + half];
    GATHER(s, a0);
  }
  if (k < cnt) {  // odd tail: both halves load same row; count it in half 0 only
    int s = col[start + k];
    if (!half) {
      GATHER(s, a1);
    }
  }
#undef GATHER

  float4 acc;
  acc.x = (a0.x + a1.x) + (a2.x + a3.x);
  acc.y = (a0.y + a1.y) + (a2.y + a3.y);
  acc.z = (a0.z + a1.z) + (a2.z + a3.z);
  acc.w = (a0.w + a1.w) + (a2.w + a3.w);
  // cross-half combine: lanes l and l^32 hold same features, disjoint edges
  acc.x += __shfl_xor(acc.x, 32, 64);
  acc.y += __shfl_xor(acc.y, 32, 64);
  acc.z += __shfl_xor(acc.z, 32, 64);
  acc.w += __shfl_xor(acc.w, 32, 64);

  if (!half) {
    const __half2* sp = reinterpret_cast<const __half2*>(hs + (size_t)node * 128 + fo);
    float2 s0 = __half22float2(sp[0]);
    float2 s1 = __half22float2(sp[1]);
    float di = dinv[node];
    float4 bv = *reinterpret_cast<const float4*>(bias + fo);
    float4 o;
    o.x = fmaf(di, acc.x + s0.x, bv.x);
    o.y = fmaf(di, acc.y + s0.y, bv.y);
    o.z = fmaf(di, acc.z + s1.x, bv.z);
    o.w = fmaf(di, acc.w + s1.y, bv.w);
    if (RELU_OUT) {
      o.x = fmaxf(o.x, 0.f); o.y = fmaxf(o.y, 0.f);
      o.z = fmaxf(o.z, 0.f); o.w = fmaxf(o.w, 0.f);
    }
    *reinterpret_cast<float4*>(out + (size_t)node * 128 + fo) = o;
  }
}

extern "C" void kernel_launch(void* const* d_in, const int* in_sizes, int n_in,
                              void* d_out, int out_size, void* d_ws, size_t ws_size,
                              hipStream_t stream) {
  const float* x  = (const float*)d_in[0];
  const int*   ei = (const int*)d_in[1];
  const float* W1 = (const float*)d_in[2];
  const float* b1 = (const float*)d_in[3];
  const float* W2 = (const float*)d_in[4];
  const float* b2 = (const float*)d_in[5];
  float* out = (float*)d_out;

  const int N = in_sizes[0] / 128;
  const int E = in_sizes[1] / 2;
  const int B = (N + 127) >> 7;
  const int* src = ei;
  const int* dst = ei + E;

  char* ws = (char*)d_ws;
  int*    bcnt    = (int*)   (ws);
  int*    boff    = (int*)   (ws + 16 * 1024);
  float*  dinv    = (float*) (ws + 64 * 1024);
  int*    rowptr  = (int*)   (ws + 512 * 1024);
  int*    col     = (int*)   (ws + 1 * MB);
  __half* h       = (__half*)(ws + 14 * MB);
  float*  agg     = (float*) (ws + 63 * MB);
  int*    staging = (int*)   (ws + 63 * MB);  // overlaps agg; dead before agg written

  dim3 b256(256);

  hipMemsetAsync(bcnt, 0, (size_t)B * 4, stream);
  k_append<<<512, b256, 0, stream>>>(src, dst, bcnt, staging, E, N, B);
  k_bscan<<<1, b256, 0, stream>>>(bcnt, boff, rowptr, B, N);
  k_build<<<B, b256, 0, stream>>>(staging, bcnt, boff, rowptr, dinv, col, N);

  dim3 ggrid((N + 63) / 64, 2);
  dim3 pgrid((N + 3) / 4);

  k_gemm<false><<<ggrid, b256, 0, stream>>>(x, W1, dinv, h, N);
  k_pull<false><<<pgrid, b256, 0, stream>>>(h, rowptr, col, dinv, b1, agg, N);

  k_gemm<true><<<ggrid, b256, 0, stream>>>(agg, W2, dinv, h, N);
  k_pull<true><<<pgrid, b256, 0, stream>>>(h, rowptr, col, dinv, b2, out, N);
}

// Round 8
// 360.055 us; speedup vs baseline: 1.9103x; 1.2803x over previous
//
#include <hip/hip_runtime.h>
#include <hip/hip_fp16.h>
#include <math.h>

// GCN 2-layer forward. Round 8: GEMM -> fp16 MFMA (16x16x32_f16, f32 acc).
// Pull unchanged (fp16 h, at L3 gather ceiling ~7.6 TB/s).
//
// ws layout (byte offsets, MiB = 1<<20):
//   0        : bcnt[B]       (i32)
//   16KB     : boff[B+1]     (i32)
//   64KB     : dinv[N]       (f32)
//   512KB    : rowptr[N+1]   (i32)
//   1MiB     : col[E]        (i32)             ~12.2 MiB (ends 13.85MB)
//   14MB-128K: Wt1, Wt2      (f16 128x128 each, transposed [n][k])
//   14MiB    : h[N*128]      (f16)             ~24.4 MiB
//   63MiB    : agg[N*128]    (f32)             ~48.9 MiB  (written after build)
//   63MiB    : staging[B*5120] (i32) OVERLAPS agg: dead before agg written

#define MB (1u << 20)
#define BCAP 5120

typedef _Float16 f16x8 __attribute__((ext_vector_type(8)));
typedef float f32x4 __attribute__((ext_vector_type(4)));

__global__ __launch_bounds__(256) void k_append(const int* __restrict__ src,
                                                const int* __restrict__ dst,
                                                int* __restrict__ bcnt,
                                                int* __restrict__ staging,
                                                int E, int N, int B) {
  __shared__ int lh[1024];
  __shared__ int lb[1024];
  const int t = threadIdx.x;
  const int per = (E + gridDim.x - 1) / gridDim.x;
  const int e0 = blockIdx.x * per;
  const int e1 = min(e0 + per, E);

  for (int i = t; i < B; i += 256) lh[i] = 0;
  __syncthreads();
  for (int e = e0 + t; e < e1; e += 256) {
    int d = dst[e], s = src[e];
    if ((unsigned)d < (unsigned)N && (unsigned)s < (unsigned)N)
      atomicAdd(&lh[d >> 7], 1);
  }
  __syncthreads();
  for (int i = t; i < B; i += 256) {
    int c = lh[i];
    lb[i] = c ? atomicAdd(&bcnt[i], c) : 0;
  }
  __syncthreads();
  for (int i = t; i < B; i += 256) lh[i] = 0;
  __syncthreads();
  for (int e = e0 + t; e < e1; e += 256) {
    int d = dst[e], s = src[e];
    if ((unsigned)d < (unsigned)N && (unsigned)s < (unsigned)N) {
      int b = d >> 7;
      int lp = atomicAdd(&lh[b], 1);
      int pos = lb[b] + lp;
      if (pos < BCAP)
        staging[(size_t)b * BCAP + pos] = ((d & 127) << 25) | s;
    }
  }
}

__global__ __launch_bounds__(256) void k_bscan(const int* __restrict__ bcnt,
                                               int* __restrict__ boff,
                                               int* __restrict__ rowptr,
                                               int B, int N) {
  __shared__ int sh[256];
  const int t = threadIdx.x;
  const int per = (B + 255) / 256;
  const int base = t * per;
  int s = 0;
  for (int j = 0; j < per; j++) {
    int i = base + j;
    if (i < B) s += min(bcnt[i], BCAP);
  }
  sh[t] = s;
  __syncthreads();
  for (int d = 1; d < 256; d <<= 1) {
    int v = (t >= d) ? sh[t - d] : 0;
    __syncthreads();
    sh[t] += v;
    __syncthreads();
  }
  int excl = (t == 0) ? 0 : sh[t - 1];
  for (int j = 0; j < per; j++) {
    int i = base + j;
    if (i < B) {
      boff[i] = excl;
      excl += min(bcnt[i], BCAP);
    }
  }
  if (t == 255) {
    boff[B] = sh[255];
    rowptr[N] = sh[255];
  }
}

__global__ __launch_bounds__(256) void k_build(const int* __restrict__ staging,
                                               const int* __restrict__ bcnt,
                                               const int* __restrict__ boff,
                                               int* __restrict__ rowptr,
                                               float* __restrict__ dinv,
                                               int* __restrict__ col, int N) {
  __shared__ int cnts[128];
  __shared__ int off[128];
  __shared__ int cur[128];
  const int b = blockIdx.x;
  const int t = threadIdx.x;
  int cnt = min(bcnt[b], BCAP);
  const int* stg = staging + (size_t)b * BCAP;

  if (t < 128) cnts[t] = 0;
  __syncthreads();
  for (int i = t; i < cnt; i += 256)
    atomicAdd(&cnts[((unsigned)stg[i]) >> 25], 1);
  __syncthreads();
  if (t < 128) off[t] = cnts[t];
  __syncthreads();
  for (int d = 1; d < 128; d <<= 1) {
    int v = 0;
    if (t < 128 && t >= d) v = off[t - d];
    __syncthreads();
    if (t < 128) off[t] += v;
    __syncthreads();
  }
  const int ebase = boff[b];
  if (t < 128) {
    int node = b * 128 + t;
    if (node < N) {
      int ex = off[t] - cnts[t];
      rowptr[node] = ebase + ex;
      cur[t] = ex;
      dinv[node] = rsqrtf((float)(cnts[t] + 1));
    }
  }
  __syncthreads();
  for (int i = t; i < cnt; i += 256) {
    int p = stg[i];
    int dl = ((unsigned)p) >> 25;
    int s = p & 0x1FFFFFF;
    int lp = atomicAdd(&cur[dl], 1);
    col[ebase + lp] = s;
  }
}

// Transpose+convert both weights: Wt[n*128+k] = (f16)W[k*128+n].
__global__ __launch_bounds__(256) void k_wprep(const float* __restrict__ W1,
                                               const float* __restrict__ W2,
                                               _Float16* __restrict__ Wt1,
                                               _Float16* __restrict__ Wt2) {
  int idx = blockIdx.x * 256 + threadIdx.x;
  if (idx >= 2 * 16384) return;
  const float* W = (idx < 16384) ? W1 : W2;
  _Float16* Wt = (idx < 16384) ? Wt1 : Wt2;
  int i = idx & 16383;
  int k = i >> 7, n = i & 127;  // consecutive threads -> consecutive n (coalesced read)
  Wt[n * 128 + k] = (_Float16)W[k * 128 + n];
}

// H[M x 128] = (f16)(act(X)[M x 128] @ W[128 x 128]) * dinv[row].
// 64-row tile per block, 4 waves x 16 rows, MFMA 16x16x32_f16.
// LDS granule = 8 f16 (16B); swizzle g' = g ^ (row&7) (2-way max, free).
template <bool RELU_IN>
__global__ __launch_bounds__(256) void k_gemm(const float* __restrict__ X,
                                              const _Float16* __restrict__ Wt,
                                              const float* __restrict__ dinv,
                                              __half* __restrict__ H, int M) {
  __shared__ __align__(16) _Float16 Xs[64 * 128];   // 16 KB
  __shared__ __align__(16) _Float16 Ws[128 * 128];  // 32 KB, [n][k]
  const int rb = blockIdx.x * 64;
  const int t = threadIdx.x;

  // Stage X tile: 1024 granules (row 0..63, kg 0..15), f32->f16, opt ReLU.
  for (int idx = t; idx < 1024; idx += 256) {
    int row = idx >> 4, kg = idx & 15;
    int grow = rb + row;
    _Float16 tmp[8];
    if (grow < M) {
      float4 v0 = *reinterpret_cast<const float4*>(X + (size_t)grow * 128 + kg * 8);
      float4 v1 = *reinterpret_cast<const float4*>(X + (size_t)grow * 128 + kg * 8 + 4);
      if (RELU_IN) {
        v0.x = fmaxf(v0.x, 0.f); v0.y = fmaxf(v0.y, 0.f);
        v0.z = fmaxf(v0.z, 0.f); v0.w = fmaxf(v0.w, 0.f);
        v1.x = fmaxf(v1.x, 0.f); v1.y = fmaxf(v1.y, 0.f);
        v1.z = fmaxf(v1.z, 0.f); v1.w = fmaxf(v1.w, 0.f);
      }
      tmp[0] = (_Float16)v0.x; tmp[1] = (_Float16)v0.y;
      tmp[2] = (_Float16)v0.z; tmp[3] = (_Float16)v0.w;
      tmp[4] = (_Float16)v1.x; tmp[5] = (_Float16)v1.y;
      tmp[6] = (_Float16)v1.z; tmp[7] = (_Float16)v1.w;
    } else {
      #pragma unroll
      for (int j = 0; j < 8; j++) tmp[j] = (_Float16)0.f;
    }
    int g = kg ^ (row & 7);
    *reinterpret_cast<uint4*>(&Xs[row * 128 + g * 8]) = *reinterpret_cast<uint4*>(tmp);
  }
  // Stage Wt: 2048 granules (n 0..127, kg 0..15), already f16.
  for (int idx = t; idx < 2048; idx += 256) {
    int n = idx >> 4, kg = idx & 15;
    uint4 v = *reinterpret_cast<const uint4*>(Wt + n * 128 + kg * 8);
    int g = kg ^ (n & 7);
    *reinterpret_cast<uint4*>(&Ws[n * 128 + g * 8]) = v;
  }
  __syncthreads();

  const int wid = t >> 6;      // wave id 0..3 -> rows wid*16..+16
  const int l = t & 63;
  const int lrow = wid * 16 + (l & 15);  // A-frag local row
  const int kq = l >> 4;                  // k-quarter 0..3

  // Preload 4 A-frags (kc=0..3): k = kc*32 + kq*8 -> kg = kc*4 + kq
  f16x8 afrag[4];
  #pragma unroll
  for (int kc = 0; kc < 4; kc++) {
    int kg = kc * 4 + kq;
    int g = kg ^ (lrow & 7);
    afrag[kc] = *reinterpret_cast<const f16x8*>(&Xs[lrow * 128 + g * 8]);
  }
  // dinv for the 4 output rows this lane writes (row = kq*4+i within tile).
  float dv[4];
  #pragma unroll
  for (int i = 0; i < 4; i++) {
    int grow = rb + wid * 16 + kq * 4 + i;
    dv[i] = (grow < M) ? dinv[grow] : 0.f;
  }

  #pragma unroll 2
  for (int nt = 0; nt < 8; nt++) {
    const int n = nt * 16 + (l & 15);
    f32x4 acc = {};
    #pragma unroll
    for (int kc = 0; kc < 4; kc++) {
      int kg = kc * 4 + kq;
      int g = kg ^ (n & 7);
      f16x8 bfrag = *reinterpret_cast<const f16x8*>(&Ws[n * 128 + g * 8]);
      acc = __builtin_amdgcn_mfma_f32_16x16x32_f16(afrag[kc], bfrag, acc, 0, 0, 0);
    }
    #pragma unroll
    for (int i = 0; i < 4; i++) {
      int grow = rb + wid * 16 + kq * 4 + i;
      if (grow < M)
        H[(size_t)grow * 128 + nt * 16 + (l & 15)] = __float2half(acc[i] * dv[i]);
    }
  }
}

// out[i] = dinv[i]*(hs[i] + sum_j hs[col_j]) + b ; optional ReLU.
template <bool RELU_OUT>
__global__ __launch_bounds__(256) void k_pull(const __half* __restrict__ hs,
                                              const int* __restrict__ rowptr,
                                              const int* __restrict__ col,
                                              const float* __restrict__ dinv,
                                              const float* __restrict__ bias,
                                              float* __restrict__ out, int N) {
  int node = blockIdx.x * 4 + (threadIdx.x >> 6);
  if (node >= N) return;
  node = __builtin_amdgcn_readfirstlane(node);
  const int lane = threadIdx.x & 63;
  const int half = lane >> 5;
  const int fo = (lane & 31) << 2;
  const int start = __builtin_amdgcn_readfirstlane(rowptr[node]);
  const int cnt = __builtin_amdgcn_readfirstlane(rowptr[node + 1]) - start;

  float4 a0 = make_float4(0.f, 0.f, 0.f, 0.f);
  float4 a1 = a0, a2 = a0, a3 = a0;

#define GATHER(sidx, dstacc)                                                   \
  {                                                                            \
    const __half2* p_ =                                                        \
        reinterpret_cast<const __half2*>(hs + (size_t)(sidx) * 128 + fo);      \
    float2 f0_ = __half22float2(p_[0]);                                        \
    float2 f1_ = __half22float2(p_[1]);                                        \
    dstacc.x += f0_.x; dstacc.y += f0_.y;                                      \
    dstacc.z += f1_.x; dstacc.w += f1_.y;                                      \
  }

  int k = 0;
  for (; k + 8 <= cnt; k += 8) {
    int s0 = col[start + k + 0 + half];
    int s1 = col[start + k + 2 + half];
    int s2 = col[start + k + 4 + half];
    int s3 = col[start + k + 6 + half];
    GATHER(s0, a0);
    GATHER(s1, a1);
    GATHER(s2, a2);
    GATHER(s3, a3);
  }
  for (; k + 2 <= cnt; k += 2) {
    int s = col[start + k + half];
    GATHER(s, a0);
  }
  if (k < cnt) {
    int s = col[start + k];
    if (!half) {
      GATHER(s, a1);
    }
  }
#undef GATHER

  float4 acc;
  acc.x = (a0.x + a1.x) + (a2.x + a3.x);
  acc.y = (a0.y + a1.y) + (a2.y + a3.y);
  acc.z = (a0.z + a1.z) + (a2.z + a3.z);
  acc.w = (a0.w + a1.w) + (a2.w + a3.w);
  acc.x += __shfl_xor(acc.x, 32, 64);
  acc.y += __shfl_xor(acc.y, 32, 64);
  acc.z += __shfl_xor(acc.z, 32, 64);
  acc.w += __shfl_xor(acc.w, 32, 64);

  if (!half) {
    const __half2* sp = reinterpret_cast<const __half2*>(hs + (size_t)node * 128 + fo);
    float2 s0 = __half22float2(sp[0]);
    float2 s1 = __half22float2(sp[1]);
    float di = dinv[node];
    float4 bv = *reinterpret_cast<const float4*>(bias + fo);
    float4 o;
    o.x = fmaf(di, acc.x + s0.x, bv.x);
    o.y = fmaf(di, acc.y + s0.y, bv.y);
    o.z = fmaf(di, acc.z + s1.x, bv.z);
    o.w = fmaf(di, acc.w + s1.y, bv.w);
    if (RELU_OUT) {
      o.x = fmaxf(o.x, 0.f); o.y = fmaxf(o.y, 0.f);
      o.z = fmaxf(o.z, 0.f); o.w = fmaxf(o.w, 0.f);
    }
    *reinterpret_cast<float4*>(out + (size_t)node * 128 + fo) = o;
  }
}

extern "C" void kernel_launch(void* const* d_in, const int* in_sizes, int n_in,
                              void* d_out, int out_size, void* d_ws, size_t ws_size,
                              hipStream_t stream) {
  const float* x  = (const float*)d_in[0];
  const int*   ei = (const int*)d_in[1];
  const float* W1 = (const float*)d_in[2];
  const float* b1 = (const float*)d_in[3];
  const float* W2 = (const float*)d_in[4];
  const float* b2 = (const float*)d_in[5];
  float* out = (float*)d_out;

  const int N = in_sizes[0] / 128;
  const int E = in_sizes[1] / 2;
  const int B = (N + 127) >> 7;
  const int* src = ei;
  const int* dst = ei + E;

  char* ws = (char*)d_ws;
  int*      bcnt    = (int*)     (ws);
  int*      boff    = (int*)     (ws + 16 * 1024);
  float*    dinv    = (float*)   (ws + 64 * 1024);
  int*      rowptr  = (int*)     (ws + 512 * 1024);
  int*      col     = (int*)     (ws + 1 * MB);
  _Float16* Wt1     = (_Float16*)(ws + 14 * MB - 128 * 1024);
  _Float16* Wt2     = (_Float16*)(ws + 14 * MB - 64 * 1024);
  __half*   h       = (__half*)  (ws + 14 * MB);
  float*    agg     = (float*)   (ws + 63 * MB);
  int*      staging = (int*)     (ws + 63 * MB);  // overlaps agg; dead before agg written

  dim3 b256(256);

  hipMemsetAsync(bcnt, 0, (size_t)B * 4, stream);
  k_wprep<<<128, b256, 0, stream>>>(W1, W2, Wt1, Wt2);
  k_append<<<512, b256, 0, stream>>>(src, dst, bcnt, staging, E, N, B);
  k_bscan<<<1, b256, 0, stream>>>(bcnt, boff, rowptr, B, N);
  k_build<<<B, b256, 0, stream>>>(staging, bcnt, boff, rowptr, dinv, col, N);

  dim3 ggrid((N + 63) / 64);
  dim3 pgrid((N + 3) / 4);

  k_gemm<false><<<ggrid, b256, 0, stream>>>(x, Wt1, dinv, h, N);
  k_pull<false><<<pgrid, b256, 0, stream>>>(h, rowptr, col, dinv, b1, agg, N);

  k_gemm<true><<<ggrid, b256, 0, stream>>>(agg, Wt2, dinv, h, N);
  k_pull<true><<<pgrid, b256, 0, stream>>>(h, rowptr, col, dinv, b2, out, N);
}